// Round 9
// baseline (308.367 us; speedup 1.0000x reference)
//
#include <hip/hip_runtime.h>
#include <hip/hip_bf16.h>

// GraphConv x2 + per-type linear + edge MLP + softmax(2).
// R8b: true pipeline overlap. K0 = fold + W-swizzle + cursor zero (tiny).
//      K1 = passA (coarse radix partition, blocks first) || mfma y=x@W + gx
//      (independent of the sort -> co-schedules). K2 = passB CSR build alone.
//      K3 gather (nontemporal val stream), K4 edge softmax.
//      (fix: nontemporal stores via native ext_vector float2)

#define H 128
#define CAPC 6656          // coarse-bucket capacity (mean ~5.1K, +20 sigma)

typedef __attribute__((ext_vector_type(8))) short bf16x8;
typedef __attribute__((ext_vector_type(4))) float f32x4;
typedef __attribute__((ext_vector_type(2))) float f32x2;

__device__ __forceinline__ unsigned short f2bf(float f) {
    unsigned u = __float_as_uint(f);
    unsigned r = (u + 0x7fffu + ((u >> 16) & 1u)) >> 16;   // RNE
    return (unsigned short)r;
}
__device__ __forceinline__ float bflo(unsigned b) { return __uint_as_float(b << 16); }
__device__ __forceinline__ float bfhi(unsigned b) { return __uint_as_float(b & 0xffff0000u); }
__device__ __forceinline__ float bfu(unsigned short b) { return __uint_as_float((unsigned)b << 16); }

// ==== K0: block0 = fold mats; blocks1-2 = W swizzle; block3 = zero cursors
// mats layout: Ax[256] | Ah[256] | Bx[256] | Bh[256] | cu[2] | ci[2]
__global__ __launch_bounds__(256) void k0_prep(
    const float* __restrict__ W0, const float* __restrict__ W1,
    const float* __restrict__ W2, const float* __restrict__ b2,
    const float* __restrict__ W3, const float* __restrict__ b3,
    const float* __restrict__ Wp, const float* __restrict__ bp,
    float* __restrict__ mats,
    unsigned short* __restrict__ WswU, unsigned short* __restrict__ WswI,
    int* __restrict__ gCur, int curWords) {
    int bx = blockIdx.x, t = threadIdx.x;
    if (bx == 0) {
        int j = t >> 1, c = t & 1;
        float ax = 0.f, ah = 0.f, bx2 = 0.f, bh = 0.f;
        for (int m = 0; m < H; ++m) {
            float wpu = Wp[m * 2 + c];
            float wpi = Wp[(H + m) * 2 + c];
            ax += W2[j * H + m] * wpu;
            ah += W2[(H + j) * H + m] * wpu;
            bx2 += W3[j * H + m] * wpi;
            bh += W3[(H + j) * H + m] * wpi;
        }
        mats[      j * 2 + c] = ax;
        mats[256 + j * 2 + c] = ah;
        mats[512 + j * 2 + c] = bx2;
        mats[768 + j * 2 + c] = bh;
        if (t < 2) {
            float s1 = 0.f, s2 = 0.f;
            for (int m = 0; m < H; ++m) {
                s1 += b2[m] * Wp[m * 2 + t];
                s2 += b3[m] * Wp[(H + m) * 2 + t];
            }
            mats[1024 + t] = s1 + bp[t];
            mats[1026 + t] = s2;
        }
        return;
    }
    if (bx <= 2) {
        const float* W = (bx == 1) ? W0 : W1;
        unsigned short* o = (bx == 1) ? WswU : WswI;
        for (int i = t; i < 4096; i += 256) {
            float4 w = ((const float4*)W)[i];
            int k = i >> 5, n0 = (i & 31) * 4;
            int kb = k >> 3, kj = k & 7;
            o[(kb * 128 + n0 + 0) * 8 + kj] = f2bf(w.x);
            o[(kb * 128 + n0 + 1) * 8 + kj] = f2bf(w.y);
            o[(kb * 128 + n0 + 2) * 8 + kj] = f2bf(w.z);
            o[(kb * 128 + n0 + 3) * 8 + kj] = f2bf(w.w);
        }
        return;
    }
    for (int i = t; i < curWords; i += 256) gCur[i] = 0;
}

// ==== K1: blocks [0,PA) = passA coarse partition; rest = mfma y/gx =======
__global__ __launch_bounds__(256) void k1_pA_mfma(
    const int* __restrict__ src, const int* __restrict__ dst,
    int* __restrict__ gCurU, int* __restrict__ gCurI,
    unsigned* __restrict__ pairU, unsigned* __restrict__ pairI,
    const float* __restrict__ xU, const float* __restrict__ xI,
    const unsigned short* __restrict__ WswU, const unsigned short* __restrict__ WswI,
    unsigned short* __restrict__ yU, unsigned short* __restrict__ yI,
    const float* __restrict__ mats,
    float2* __restrict__ gxU, float2* __restrict__ gxI,
    int E, int ncu, int nci, int NU, int NI, int PA, int NBU) {
    __shared__ __align__(16) char SMEM[34816];
    int t = threadIdx.x;

    if (blockIdx.x < (unsigned)PA) {
        // ---- passA: coarse partition (user key = s>>9, item key = d>>8) --
        int* cntU  = (int*)SMEM;
        int* baseU = cntU + 256;
        int* cntI  = baseU + 256;
        int* baseI = cntI + 256;
        int t0 = blockIdx.x * 4096;
        cntU[t] = 0; cntI[t] = 0;
        __syncthreads();
        #pragma unroll
        for (int j = 0; j < 16; ++j) {
            int e = t0 + j * 256 + t;
            if (e < E) { atomicAdd(&cntU[src[e] >> 9], 1); atomicAdd(&cntI[dst[e] >> 8], 1); }
        }
        __syncthreads();
        if (t < ncu) { int c = cntU[t]; baseU[t] = c ? (CAPC * t + atomicAdd(&gCurU[t], c)) : 0; }
        if (t < nci) { int c = cntI[t]; baseI[t] = c ? (CAPC * t + atomicAdd(&gCurI[t], c)) : 0; }
        __syncthreads();
        #pragma unroll
        for (int j = 0; j < 16; ++j) {
            int e = t0 + j * 256 + t;
            if (e < E) {
                int s = src[e], d = dst[e];
                int bu = s >> 9, bi = d >> 8;
                int r1 = atomicSub(&cntU[bu], 1) - 1;
                int i1 = baseU[bu] + r1;
                if (i1 < CAPC * (bu + 1))
                    pairU[i1] = ((unsigned)(s & 511) << 20) | (unsigned)d;
                int r2 = atomicSub(&cntI[bi], 1) - 1;
                int i2 = baseI[bi] + r2;
                if (i2 < CAPC * (bi + 1))
                    pairI[i2] = ((unsigned)(d & 255) << 20) | (unsigned)s;
            }
        }
        return;
    }

    // ---- mfma: y = x @ W (bf16, unscaled) + gx = x·Mx + cv --------------
    unsigned short* As = (unsigned short*)SMEM;   // [kb][m][8], 32 KB
    int mb = blockIdx.x - PA;
    bool us = mb < NBU;
    int tile = us ? mb : mb - NBU;
    const float* x = us ? xU : xI;
    const unsigned short* Wsw = us ? WswU : WswI;
    unsigned short* y = us ? yU : yI;
    const float* Mx = mats + (us ? 0 : 512);
    const float* cv = mats + (us ? 1024 : 1026);
    float2* gx = us ? gxU : gxI;
    int n = us ? NU : NI;
    int row0 = tile << 7;

    for (int it = 0; it < 16; ++it) {
        int i = it * 256 + t;
        int m = i >> 5, c4 = i & 31;
        int row = row0 + m;
        float4 v = (row < n) ? ((const float4*)x)[(size_t)row * 32 + c4]
                             : make_float4(0.f, 0.f, 0.f, 0.f);
        int k0 = c4 * 4;
        ushort4 s4; s4.x = f2bf(v.x); s4.y = f2bf(v.y); s4.z = f2bf(v.z); s4.w = f2bf(v.w);
        *(ushort4*)&As[((k0 >> 3) * 128 + m) * 8 + (k0 & 7)] = s4;
    }
    __syncthreads();

    int w = t >> 6, l = t & 63;
    int lane15 = l & 15, quad = l >> 4;

    f32x4 acc[2][8];
    #pragma unroll
    for (int rt = 0; rt < 2; ++rt)
        #pragma unroll
        for (int c = 0; c < 8; ++c) acc[rt][c] = (f32x4){0.f, 0.f, 0.f, 0.f};

    #pragma unroll
    for (int ks = 0; ks < 4; ++ks) {
        int kb = ks * 4 + quad;
        bf16x8 a0 = *(const bf16x8*)&As[(kb * 128 + w * 32 + lane15) * 8];
        bf16x8 a1 = *(const bf16x8*)&As[(kb * 128 + w * 32 + 16 + lane15) * 8];
        #pragma unroll
        for (int c = 0; c < 8; ++c) {
            bf16x8 b = *(const bf16x8*)&Wsw[(size_t)(kb * 128 + c * 16 + lane15) * 8];
            acc[0][c] = __builtin_amdgcn_mfma_f32_16x16x32_bf16(a0, b, acc[0][c], 0, 0, 0);
            acc[1][c] = __builtin_amdgcn_mfma_f32_16x16x32_bf16(a1, b, acc[1][c], 0, 0, 0);
        }
    }

    {   // gx from As (bf16 x): 2 threads per row
        int row = t >> 1, cc = t & 1;
        float p = 0.f;
        for (int kb = 0; kb < 16; ++kb) {
            const unsigned short* ap = &As[(kb * 128 + row) * 8];
            #pragma unroll
            for (int j = 0; j < 8; ++j)
                p += bfu(ap[j]) * Mx[(kb * 8 + j) * 2 + cc];
        }
        int grow = row0 + row;
        if (grow < n) ((float*)&gx[grow])[cc] = p + cv[cc];
    }
    __syncthreads();                       // all As reads done; reuse LDS

    const int LSTR = 136;                  // 128x136 ushorts = 34816 B exactly
    unsigned short* SMu = (unsigned short*)SMEM;
    unsigned short* Lw = SMu + w * 32 * LSTR;
    #pragma unroll
    for (int rt = 0; rt < 2; ++rt) {
        #pragma unroll
        for (int r = 0; r < 4; ++r) {
            int lrow = rt * 16 + quad * 4 + r;
            #pragma unroll
            for (int c = 0; c < 8; ++c)
                Lw[lrow * LSTR + c * 16 + lane15] = f2bf(acc[rt][c][r]);
        }
    }
    #pragma unroll
    for (int pass = 0; pass < 8; ++pass) {
        int lrow = pass * 4 + quad;
        int grow = row0 + w * 32 + lrow;
        uint4 v = *(uint4*)&Lw[lrow * LSTR + lane15 * 8];
        if (grow < n) *(uint4*)&y[(size_t)grow * 128 + lane15 * 8] = v;
    }
}

// ==== K2: passB CSR build (one block per coarse bucket) ==================
__global__ __launch_bounds__(256) void k2_passB(
    const unsigned* __restrict__ pairU, const unsigned* __restrict__ pairI,
    const int* __restrict__ gCurU, const int* __restrict__ gCurI,
    int2* __restrict__ offU, int2* __restrict__ offI,
    float* __restrict__ invU, float* __restrict__ invI,
    int* __restrict__ valU, int* __restrict__ valI,
    int NU, int NI, int ncu) {
    __shared__ __align__(16) char SMEM[34816];
    int t = threadIdx.x;
    bool us = blockIdx.x < (unsigned)ncu;
    int cb = us ? blockIdx.x : blockIdx.x - ncu;
    const unsigned* pairs = us ? pairU : pairI;
    int size = us ? gCurU[cb] : gCurI[cb];
    if (size > CAPC) size = CAPC;
    int start = cb * CAPC;
    int nodesPer = us ? 512 : 256;
    int nodeBase = cb * nodesPer;
    int n = us ? NU : NI;
    int2* off = us ? offU : offI;
    float* inv = us ? invU : invI;
    int* val = us ? valU : valI;

    int* cnt  = (int*)SMEM;            // nodesPer
    int* pref = cnt + nodesPer;        // nodesPer
    int* part = pref + nodesPer;       // 256
    int* stage = part + 256;           // CAPC

    for (int i = t; i < nodesPer; i += 256) cnt[i] = 0;
    __syncthreads();
    for (int i = t; i < size; i += 256) atomicAdd(&cnt[pairs[start + i] >> 20], 1);
    __syncthreads();
    int g = nodesPer >> 8;             // 2 (users) or 1 (items)
    int b0 = t * g;
    int lv0 = cnt[b0], lv1 = (g == 2) ? cnt[b0 + 1] : 0;
    int lsum = lv0 + lv1;
    part[t] = lsum; __syncthreads();
    for (int o2 = 1; o2 < 256; o2 <<= 1) {
        int v = (t >= o2) ? part[t - o2] : 0; __syncthreads();
        part[t] += v; __syncthreads();
    }
    int excl = part[t] - lsum;
    pref[b0] = excl;
    if (g == 2) pref[b0 + 1] = excl + lv0;
    __syncthreads();
    for (int i = t; i < nodesPer; i += 256) {
        int node = nodeBase + i;
        if (node < n) {
            int st = pref[i];
            off[node] = make_int2(start + st, start + st + cnt[i]);
            inv[node] = rsqrtf(fmaxf((float)cnt[i], 1.0f));
        }
    }
    __syncthreads();
    for (int i = t; i < size; i += 256) {
        unsigned p = pairs[start + i];
        int r = atomicAdd(&pref[p >> 20], 1);
        stage[r] = (int)(p & 0xFFFFFu);
    }
    __syncthreads();
    for (int i = t; i < size; i += 256) val[start + i] = stage[i];
}

// ==== K3: gather (both sides), 16 lanes/node, per-neighbor invo fma ======
__global__ __launch_bounds__(256) void gather_kernel(
    const int2* __restrict__ offU, const int* __restrict__ valU,
    const int2* __restrict__ offI, const int* __restrict__ valI,
    const unsigned short* __restrict__ yU, const unsigned short* __restrict__ yI,
    const float* __restrict__ invU, const float* __restrict__ invI,
    const float* __restrict__ b0, const float* __restrict__ b1,
    const float* __restrict__ mats,
    const float2* __restrict__ gxU, const float2* __restrict__ gxI,
    float2* __restrict__ su, float2* __restrict__ si,
    int NU, int NI, int GU) {
    bool us = blockIdx.x < (unsigned)GU;
    int nb = us ? blockIdx.x : blockIdx.x - GU;
    const int2* off = us ? offU : offI;
    const int* val = us ? valU : valI;
    const unsigned short* yo = us ? yI : yU;
    const float* invo = us ? invI : invU;     // neighbor-side inv (deferred)
    const float* inv = us ? invU : invI;
    const float* bv = us ? b1 : b0;
    const float* Mh = mats + (us ? 256 : 768);
    const float2* gx = us ? gxU : gxI;
    float2* so = us ? su : si;
    int n = us ? NU : NI;

    int g = threadIdx.x >> 4, t = threadIdx.x & 15, j0 = t * 8;
    int u = nb * 16 + g;
    if (u >= n) return;

    float a0 = 0, a1 = 0, a2 = 0, a3 = 0, a4 = 0, a5 = 0, a6 = 0, a7 = 0;
    int2 oe = off[u];
    int k = oe.x, end = oe.y;
    for (; k + 4 <= end; k += 4) {
        int v0 = __builtin_nontemporal_load(val + k);
        int v1 = __builtin_nontemporal_load(val + k + 1);
        int v2 = __builtin_nontemporal_load(val + k + 2);
        int v3 = __builtin_nontemporal_load(val + k + 3);
        float i0 = invo[v0], i1 = invo[v1], i2 = invo[v2], i3 = invo[v3];
        uint4 w0 = *(const uint4*)(yo + (size_t)v0 * H + j0);
        uint4 w1 = *(const uint4*)(yo + (size_t)v1 * H + j0);
        uint4 w2 = *(const uint4*)(yo + (size_t)v2 * H + j0);
        uint4 w3 = *(const uint4*)(yo + (size_t)v3 * H + j0);
        a0 += bflo(w0.x) * i0 + bflo(w1.x) * i1 + bflo(w2.x) * i2 + bflo(w3.x) * i3;
        a1 += bfhi(w0.x) * i0 + bfhi(w1.x) * i1 + bfhi(w2.x) * i2 + bfhi(w3.x) * i3;
        a2 += bflo(w0.y) * i0 + bflo(w1.y) * i1 + bflo(w2.y) * i2 + bflo(w3.y) * i3;
        a3 += bfhi(w0.y) * i0 + bfhi(w1.y) * i1 + bfhi(w2.y) * i2 + bfhi(w3.y) * i3;
        a4 += bflo(w0.z) * i0 + bflo(w1.z) * i1 + bflo(w2.z) * i2 + bflo(w3.z) * i3;
        a5 += bfhi(w0.z) * i0 + bfhi(w1.z) * i1 + bfhi(w2.z) * i2 + bfhi(w3.z) * i3;
        a6 += bflo(w0.w) * i0 + bflo(w1.w) * i1 + bflo(w2.w) * i2 + bflo(w3.w) * i3;
        a7 += bfhi(w0.w) * i0 + bfhi(w1.w) * i1 + bfhi(w2.w) * i2 + bfhi(w3.w) * i3;
    }
    for (; k < end; ++k) {
        int v0 = __builtin_nontemporal_load(val + k);
        float i0 = invo[v0];
        uint4 w0 = *(const uint4*)(yo + (size_t)v0 * H + j0);
        a0 += bflo(w0.x) * i0; a1 += bfhi(w0.x) * i0;
        a2 += bflo(w0.y) * i0; a3 += bfhi(w0.y) * i0;
        a4 += bflo(w0.z) * i0; a5 += bfhi(w0.z) * i0;
        a6 += bflo(w0.w) * i0; a7 += bfhi(w0.w) * i0;
    }
    float iv = inv[u];
    float4 bb0 = *(const float4*)(bv + j0), bb1 = *(const float4*)(bv + j0 + 4);
    float h0 = fmaxf(a0 * iv + bb0.x, 0.f), h1 = fmaxf(a1 * iv + bb0.y, 0.f);
    float h2 = fmaxf(a2 * iv + bb0.z, 0.f), h3 = fmaxf(a3 * iv + bb0.w, 0.f);
    float h4 = fmaxf(a4 * iv + bb1.x, 0.f), h5 = fmaxf(a5 * iv + bb1.y, 0.f);
    float h6 = fmaxf(a6 * iv + bb1.z, 0.f), h7 = fmaxf(a7 * iv + bb1.w, 0.f);
    float4 m0 = *(const float4*)(Mh + j0 * 2),      m1 = *(const float4*)(Mh + j0 * 2 + 4);
    float4 m2 = *(const float4*)(Mh + j0 * 2 + 8),  m3 = *(const float4*)(Mh + j0 * 2 + 12);
    float p0 = h0 * m0.x + h1 * m0.z + h2 * m1.x + h3 * m1.z
             + h4 * m2.x + h5 * m2.z + h6 * m3.x + h7 * m3.z;
    float p1 = h0 * m0.y + h1 * m0.w + h2 * m1.y + h3 * m1.w
             + h4 * m2.y + h5 * m2.w + h6 * m3.y + h7 * m3.w;
    #pragma unroll
    for (int o = 1; o < 16; o <<= 1) { p0 += __shfl_xor(p0, o); p1 += __shfl_xor(p1, o); }
    if (t == 0) {
        float2 gg = gx[u];
        so[u] = make_float2(p0 + gg.x, p1 + gg.y);
    }
}

__global__ void edge_kernel(const int* __restrict__ src, const int* __restrict__ dst,
                            const float2* __restrict__ su, const float2* __restrict__ si,
                            float* __restrict__ out, int E) {
    int e0 = (blockIdx.x * 256 + threadIdx.x) * 2;
    if (e0 >= E) return;
    int2 s2 = *(const int2*)(src + e0);
    int2 d2 = *(const int2*)(dst + e0);
    float2 a = su[s2.x], b = si[d2.x];
    float l0 = a.x + b.x, l1 = a.y + b.y;
    float m = fmaxf(l0, l1);
    float q0 = __expf(l0 - m), q1 = __expf(l1 - m);
    float r = 1.0f / (q0 + q1);
    __builtin_nontemporal_store((f32x2){q0 * r, q1 * r}, (f32x2*)(out + (size_t)e0 * 2));
    if (e0 + 1 < E) {
        a = su[s2.y]; b = si[d2.y];
        l0 = a.x + b.x; l1 = a.y + b.y;
        m = fmaxf(l0, l1);
        q0 = __expf(l0 - m); q1 = __expf(l1 - m);
        r = 1.0f / (q0 + q1);
        __builtin_nontemporal_store((f32x2){q0 * r, q1 * r}, (f32x2*)(out + (size_t)(e0 + 1) * 2));
    }
}

extern "C" void kernel_launch(void* const* d_in, const int* in_sizes, int n_in,
                              void* d_out, int out_size, void* d_ws, size_t ws_size,
                              hipStream_t stream) {
    const float* x_user = (const float*)d_in[0];
    const float* x_item = (const float*)d_in[1];
    const float* W0 = (const float*)d_in[2];
    const float* b0 = (const float*)d_in[3];
    const float* W1 = (const float*)d_in[4];
    const float* b1 = (const float*)d_in[5];
    const float* W2 = (const float*)d_in[6];
    const float* b2 = (const float*)d_in[7];
    const float* W3 = (const float*)d_in[8];
    const float* b3 = (const float*)d_in[9];
    const float* Wp = (const float*)d_in[10];
    const float* bp = (const float*)d_in[11];
    const int* esrc = (const int*)d_in[12];
    const int* edst = (const int*)d_in[13];

    const int NU = in_sizes[0] / H;
    const int NI = in_sizes[1] / H;
    const int E  = in_sizes[12];
    const int NCU = (NU + 511) >> 9;          // coarse buckets (512 nodes)
    const int NCI = (NI + 255) >> 8;          // coarse buckets (256 nodes)
    const int NBU = (NU + 127) >> 7;          // mfma tiles
    const int NBI = (NI + 127) >> 7;
    const int GU = (NU + 15) >> 4, GI = (NI + 15) >> 4;

    auto rnd = [](size_t x) { return (x + 63) & ~(size_t)63; };
    char* base = (char*)d_ws;
    size_t o = 0;
    auto alloc = [&](size_t elems) { void* p = base + o * 4; o += rnd(elems); return p; };

    float* inv_du = (float*)alloc(NU);
    float* inv_di = (float*)alloc(NI);
    float2* su    = (float2*)alloc((size_t)NU * 2);
    float2* si    = (float2*)alloc((size_t)NI * 2);
    float2* gxU   = (float2*)alloc((size_t)NU * 2);
    float2* gxI   = (float2*)alloc((size_t)NI * 2);
    float* mats   = (float*)alloc(1056);
    size_t cur_off = o;
    int* gCurU = (int*)alloc(NCU);
    int* gCurI = (int*)alloc(NCI);
    size_t cur_words = o - cur_off;
    int2* offU = (int2*)alloc((size_t)NU * 2);
    int2* offI = (int2*)alloc((size_t)NI * 2);
    int* valU  = (int*)alloc((size_t)NCU * CAPC);
    int* valI  = (int*)alloc((size_t)NCI * CAPC);
    unsigned* pairU = (unsigned*)alloc((size_t)NCU * CAPC);
    unsigned* pairI = (unsigned*)alloc((size_t)NCI * CAPC);
    unsigned short* WswU = (unsigned short*)alloc(8192);
    unsigned short* WswI = (unsigned short*)alloc(8192);
    unsigned short* yU = (unsigned short*)alloc((size_t)NU * 64);
    unsigned short* yI = (unsigned short*)alloc((size_t)NI * 64);

    k0_prep<<<4, 256, 0, stream>>>(
        W0, W1, W2, b2, W3, b3, Wp, bp, mats, WswU, WswI, gCurU, (int)cur_words);

    int PA = (E + 4095) / 4096;
    k1_pA_mfma<<<PA + NBU + NBI, 256, 0, stream>>>(
        esrc, edst, gCurU, gCurI, pairU, pairI,
        x_user, x_item, WswU, WswI, yU, yI, mats, gxU, gxI,
        E, NCU, NCI, NU, NI, PA, NBU);

    k2_passB<<<NCU + NCI, 256, 0, stream>>>(
        pairU, pairI, gCurU, gCurI, offU, offI, inv_du, inv_di, valU, valI,
        NU, NI, NCU);

    gather_kernel<<<GU + GI, 256, 0, stream>>>(
        offU, valU, offI, valI, yU, yI, inv_du, inv_di, b0, b1, mats,
        gxU, gxI, su, si, NU, NI, GU);

    edge_kernel<<<(E / 2 + 255) / 256, 256, 0, stream>>>(esrc, edst, su, si, (float*)d_out, E);
}